// Round 1
// baseline (97.198 us; speedup 1.0000x reference)
//
#include <hip/hip_runtime.h>

// Problem: B=4, H=8, L=128, D=64. All fp32.  n = b*8+h in [0,32).
// K0: per-row softmax(Q), softmax(K), entropies — 1024 blocks x 4-row waves;
//     block 0 also zeroes the 16-double t-stat accumulators (ws is poisoned).
// KA: J via JSD identity, 1024 blocks x 4-row tiles, pK staged via float4.
// KC: per-head stats redundantly per block, gate x via S/D algebra, T=J·x,
//     He, t; per-block t-partials folded into per-head double atomics.
// KD: pure streaming BN write (stats are 2 doubles per head, precombined).
// MATH RULES (hard-won):
//   * __log2f/__expf/__fdividef — HIP fast intrinsics -> native v_log/v_exp/
//     v_rcp. These are the ONLY fast transcendental spellings that work here.
//   * plain log2f/exp2f -> OCML precise (~25 VALU) — R8's 51us ka_J.
//   * __exp2f -> glibc collision, compile error (R7).
//   * __builtin_amdgcn_logf / inline-asm v_log_f32 -> container death (R5/R6/R9).

#define EPS 1e-6f
#define BN_EPS 1e-5f

// ---------------- K0: 1024 blocks x 256 threads ------------------------------
// One wave per (b,h,l) row: softmax(Q)->pQ,Sq; softmax(K)->pK,Sk; entropy(V).
__global__ void __launch_bounds__(256) k0_rows(
    const float* __restrict__ Q, const float* __restrict__ K,
    const float* __restrict__ V,
    float* __restrict__ pQ, float* __restrict__ pK,
    float* __restrict__ Sq, float* __restrict__ Sk,
    float* __restrict__ hi, float* __restrict__ h_raw,
    double* __restrict__ tacc)
{
    const int tid = threadIdx.x;
    const int wave = tid >> 6, lane = tid & 63;
    const int r = blockIdx.x * 4 + wave;   // 0..4095
    const int base = r * 64 + lane;

    // zero the per-head t-stat accumulators (workspace arrives poisoned)
    if (blockIdx.x == 0 && tid < 16) tacc[tid] = 0.0;

    // K softmax + Sk
    float kk = K[base];
    float m = kk;
    for (int off = 32; off; off >>= 1) m = fmaxf(m, __shfl_xor(m, off));
    float e = __expf(kk - m);
    float s = e;
    for (int off = 32; off; off >>= 1) s += __shfl_xor(s, off);
    const float pk = e * __fdividef(1.0f, s);
    pK[base] = pk;
    float pl = pk * __log2f(pk);
    for (int off = 32; off; off >>= 1) pl += __shfl_xor(pl, off);
    if (lane == 0) Sk[r] = pl;

    // Q softmax + Sq
    float q = Q[base];
    m = q;
    for (int off = 32; off; off >>= 1) m = fmaxf(m, __shfl_xor(m, off));
    e = __expf(q - m);
    s = e;
    for (int off = 32; off; off >>= 1) s += __shfl_xor(s, off);
    const float pq = e * __fdividef(1.0f, s);
    pQ[base] = pq;
    pl = pq * __log2f(pq);
    for (int off = 32; off; off >>= 1) pl += __shfl_xor(pl, off);
    if (lane == 0) Sq[r] = pl;

    // V entropy
    float v = V[base];
    s = v;
    for (int off = 32; off; off >>= 1) s += __shfl_xor(s, off);
    float vn = v * __fdividef(1.0f, s + EPS);
    vn = fminf(fmaxf(vn, EPS), 1.0f);
    const float hv = -vn * __log2f(vn);
    hi[base] = hv;
    float hs = hv;
    for (int off = 32; off; off >>= 1) hs += __shfl_xor(hs, off);
    if (lane == 0) h_raw[r] = hs;
}

// ---------------- KA: 1024 blocks x 256 threads ------------------------------
// Block = (n, 4-row tile). Stage pK head-slice into LDS (float4, pad 65),
// J via JSD identity: J = 0.5*(Sq(i)+Sk(j) - sum_d s*log2(s/2+EPS)), s=q+k.
// Wave w -> row i0+w; lane -> cols {lane, lane+64}.
__global__ void __launch_bounds__(256) ka_J(
    const float* __restrict__ pQ, const float* __restrict__ pK,
    const float* __restrict__ Sq, const float* __restrict__ Sk,
    float* __restrict__ J, float* __restrict__ Sg, float* __restrict__ Dg,
    double* __restrict__ Jpart)
{
    __shared__ float sK[128 * 65];   // pad 65 -> conflict-free strided reads
    __shared__ float sQ[4 * 64];
    __shared__ float sSk[128];
    __shared__ float sSq[4];
    __shared__ double sred[8];
    const int bid = blockIdx.x;      // n*32 + tile
    const int n = bid >> 5;
    const int i0 = (bid & 31) * 4;
    const int tid = threadIdx.x;
    const int wave = tid >> 6, lane = tid & 63;

    // stage pK slice (128x64 = 2048 float4), pad to 65 floats/row
    const float4* pk4 = (const float4*)(pK + n * 8192);
    #pragma unroll
    for (int v = 0; v < 8; ++v) {
        const int idx = tid + 256 * v;
        const float4 f = pk4[idx];
        float* dst = sK + (idx >> 4) * 65 + (idx & 15) * 4;
        dst[0] = f.x; dst[1] = f.y; dst[2] = f.z; dst[3] = f.w;
    }
    sQ[tid] = pQ[(n * 128 + i0) * 64 + tid];   // 4 rows x 64, contiguous
    if (tid < 128) sSk[tid] = Sk[n * 128 + tid];
    if (tid < 4)   sSq[tid] = Sq[n * 128 + i0 + tid];
    __syncthreads();

    const float* qrow = sQ + wave * 64;
    const float* kp0 = sK + lane * 65;
    const float* kp1 = sK + (lane + 64) * 65;
    float a0 = 0.f, a1 = 0.f;
    #pragma unroll 8
    for (int d = 0; d < 64; ++d) {
        const float qv = qrow[d];
        const float s0v = qv + kp0[d];
        const float s1v = qv + kp1[d];
        a0 += s0v * __log2f(fmaf(0.5f, s0v, EPS));
        a1 += s1v * __log2f(fmaf(0.5f, s1v, EPS));
    }
    const int gi = i0 + wave;                   // row within head
    const float bq = sSq[wave];
    const float J0 = 0.5f * (bq + sSk[lane]      - a0);
    const float J1 = 0.5f * (bq + sSk[lane + 64] - a1);
    const int rbase = (n * 128 + gi) * 128;
    J[rbase + lane] = J0;
    J[rbase + lane + 64] = J1;

    // row sum + diagonal (full row lives in this wave)
    float s0 = J0 + J1;
    for (int off = 32; off; off >>= 1) s0 += __shfl_xor(s0, off);
    const float D = (gi < 64) ? __shfl(J0, gi) : __shfl(J1, gi - 64);
    if (lane == 0) { Sg[n * 128 + gi] = s0; Dg[n * 128 + gi] = D; }

    // off-diagonal double partials
    double ls = 0.0, ls2 = 0.0;
    if (lane != gi)      { ls += J0; ls2 += (double)J0 * (double)J0; }
    if (lane + 64 != gi) { ls += J1; ls2 += (double)J1 * (double)J1; }
    for (int off = 32; off; off >>= 1) {
        ls  += __shfl_xor(ls, off);
        ls2 += __shfl_xor(ls2, off);
    }
    if (lane == 0) { sred[wave] = ls; sred[4 + wave] = ls2; }
    __syncthreads();
    if (tid == 0) {
        Jpart[2 * bid]     = sred[0] + sred[1] + sred[2] + sred[3];
        Jpart[2 * bid + 1] = sred[4] + sred[5] + sred[6] + sred[7];
    }
}

// ---------------- KC: 512 blocks x 256 threads -------------------------------
// Redundant per-head prep (jstats from 128 partials, hstats, gate x via S/D
// algebra), then T = J·x for own 8 rows, He, t; t-stat partials go straight
// into per-head double atomics (64 atomic pairs per head — no contention).
__global__ void __launch_bounds__(256) kc_he(
    const float* __restrict__ J, const float* __restrict__ hi,
    const double* __restrict__ Jpart, const float* __restrict__ h_raw,
    const float* __restrict__ Sg, const float* __restrict__ Dg,
    const float* __restrict__ j_gamma, const float* __restrict__ j_beta,
    const float* __restrict__ h_gamma, const float* __restrict__ h_beta,
    float* __restrict__ t, double* __restrict__ tacc)
{
    __shared__ float sx[128], shbn[128];
    __shared__ double sred[8];
    __shared__ double st1[4], st2[4];
    __shared__ float sprm[5];        // jm, jinv, hm, hinv, C
    const int bid = blockIdx.x;
    const int n = bid >> 4;
    const int i0 = (bid & 15) * 8;
    const int hh = n & 7;
    const int tid = threadIdx.x;
    const int wave = tid >> 6, lane = tid & 63;

    // jstats: combine the head's 128 double partials (wave 0, 2 per lane)
    if (wave == 0) {
        const int p1 = lane, p2 = lane + 64;
        const int pb1 = ((p1 >> 5) * 8 + hh) * 32 + (p1 & 31);
        const int pb2 = ((p2 >> 5) * 8 + hh) * 32 + (p2 & 31);
        double s = Jpart[2 * pb1] + Jpart[2 * pb2];
        double s2 = Jpart[2 * pb1 + 1] + Jpart[2 * pb2 + 1];
        for (int off = 32; off; off >>= 1) {
            s += __shfl_xor(s, off); s2 += __shfl_xor(s2, off);
        }
        if (lane == 0) {
            const double cnt = 65024.0;          // 4*128*127
            const double mean = s / cnt;
            const double var = s2 / cnt - mean * mean;
            sprm[0] = (float)mean;
            sprm[1] = (float)(1.0 / sqrt(var + (double)BN_EPS));
        }
    }
    // h stats over 512 values (all waves)
    {
        double s = 0.0, s2 = 0.0;
        for (int p = tid; p < 512; p += 256) {
            const int b = p >> 7, l = p & 127;
            const float v = h_raw[(b * 8 + hh) * 128 + l];
            s += v; s2 += (double)v * (double)v;
        }
        for (int off = 32; off; off >>= 1) {
            s += __shfl_xor(s, off); s2 += __shfl_xor(s2, off);
        }
        if (lane == 0) { sred[wave] = s; sred[4 + wave] = s2; }
    }
    __syncthreads();
    if (tid == 0) {
        const double hs = sred[0] + sred[1] + sred[2] + sred[3];
        const double hs2 = sred[4] + sred[5] + sred[6] + sred[7];
        const double hm = hs / 512.0;
        const double hvar = hs2 / 512.0 - hm * hm;
        sprm[2] = (float)hm;
        sprm[3] = (float)(1.0 / sqrt(hvar + (double)BN_EPS));
    }
    __syncthreads();
    const float jm = sprm[0], jinv = sprm[1];
    const float hm = sprm[2], hinv = sprm[3];
    const float jg = j_gamma[hh], jb = j_beta[hh];
    // gate x + h_bn for all 128 rows (O(1) each via S/D algebra)
    if (tid < 128) {
        const int i = tid;
        const float S = Sg[n * 128 + i], D = Dg[n * 128 + i];
        const float hb = (h_raw[n * 128 + i] - hm) * hinv * h_gamma[hh] + h_beta[hh];
        const float rs = jinv * jg * (S - D - 127.0f * jm) + 127.0f * jb + D;
        sx[i] = (rs + hb < 0.0f) ? 1.0f : 0.0f;
        shbn[i] = hb;
    }
    __syncthreads();
    if (wave == 0) {                 // C = sum of gates
        float c = sx[lane] + sx[lane + 64];
        for (int off = 32; off; off >>= 1) c += __shfl_xor(c, off);
        if (lane == 0) sprm[4] = c;
    }
    __syncthreads();
    const float C = sprm[4];
    // He, t for own 8 rows; wave rb -> local rows {rb, rb+4}
    const int rb = wave;
    double bs = 0.0, bs2 = 0.0;
    for (int rr = 0; rr < 2; ++rr) {
        const int i = i0 + rb + 4 * rr;          // row within head
        const int r = n * 128 + i;
        float tr = J[r * 128 + lane] * sx[lane] + J[r * 128 + 64 + lane] * sx[lane + 64];
        for (int off = 32; off; off >>= 1) tr += __shfl_xor(tr, off);
        const float xi = sx[i], Di = Dg[r];
        const float dot = jinv * jg * (tr - xi * Di - jm * (C - xi))
                        + jb * (C - xi) + xi * Di;
        const float He = xi * (dot + shbn[i]);
        const float tv = -(He * hi[r * 64 + lane] * __fdividef(1.0f, shbn[i]));
        t[r * 64 + lane] = tv;
        double ds = tv, ds2 = (double)tv * (double)tv;
        for (int off = 32; off; off >>= 1) {
            ds += __shfl_xor(ds, off); ds2 += __shfl_xor(ds2, off);
        }
        if (lane == 0) { bs += ds; bs2 += ds2; }
    }
    if (lane == 0) { st1[wave] = bs; st2[wave] = bs2; }
    __syncthreads();
    if (tid == 0) {
        atomicAdd(&tacc[2 * hh],     st1[0] + st1[1] + st1[2] + st1[3]);
        atomicAdd(&tacc[2 * hh + 1], st2[0] + st2[1] + st2[2] + st2[3]);
    }
}

// ---------------- KD: 512 blocks x 256 threads -------------------------------
// Pure streaming BN: per-head stats are 2 precombined doubles.
__global__ void __launch_bounds__(256) kd_out(
    const double* __restrict__ tacc, const float* __restrict__ t,
    const float* __restrict__ gamma, const float* __restrict__ beta,
    float* __restrict__ out)
{
    const int bid = blockIdx.x;
    const int tid = threadIdx.x;
    const int g0 = bid * 512;              // 512 outputs per block
    const int hh = (g0 >> 13) & 7;         // uniform within block
    const double s = tacc[2 * hh], s2 = tacc[2 * hh + 1];
    const double mean = s / 32768.0;
    const double var = s2 / 32768.0 - mean * mean;
    const float tm = (float)mean;
    const float tinv = (float)(1.0 / sqrt(var + (double)BN_EPS));
    const float g = gamma[hh], be = beta[hh];
    out[g0 + tid]       = (t[g0 + tid]       - tm) * tinv * g + be;
    out[g0 + 256 + tid] = (t[g0 + 256 + tid] - tm) * tinv * g + be;
}

// ---------------------------------------------------------------- launch
extern "C" void kernel_launch(void* const* d_in, const int* in_sizes, int n_in,
                              void* d_out, int out_size, void* d_ws, size_t ws_size,
                              hipStream_t stream) {
    (void)in_sizes; (void)n_in; (void)out_size; (void)ws_size;
    const float* Q = (const float*)d_in[0];
    const float* K = (const float*)d_in[1];
    const float* V = (const float*)d_in[2];
    const float* j_gamma = (const float*)d_in[3];
    const float* j_beta  = (const float*)d_in[4];
    const float* h_gamma = (const float*)d_in[5];
    const float* h_beta  = (const float*)d_in[6];
    const float* bnH_gamma = (const float*)d_in[7];
    const float* bnH_beta  = (const float*)d_in[8];
    float* out = (float*)d_out;

    float* w = (float*)d_ws;
    float*  J     = w;                         // 524288
    float*  hi    = w + 524288;                // 262144
    float*  t     = w + 786432;                // 262144
    float*  pQ    = w + 1048576;               // 262144
    float*  pK    = w + 1310720;               // 262144 (16B-aligned for float4)
    float*  h_raw = w + 1572864;               // 4096
    float*  Sq    = w + 1576960;               // 4096
    float*  Sk    = w + 1581056;               // 4096
    float*  Sg    = w + 1585152;               // 4096
    float*  Dg    = w + 1589248;               // 4096
    double* Jpart = (double*)(w + 1593344);    // 2048 doubles (8B-aligned)
    double* tacc  = (double*)(w + 1597440);    // 16 doubles (8B-aligned)

    k0_rows<<<1024, 256, 0, stream>>>(Q, K, V, pQ, pK, Sq, Sk, hi, h_raw, tacc);
    ka_J<<<1024, 256, 0, stream>>>(pQ, pK, Sq, Sk, J, Sg, Dg, Jpart);
    kc_he<<<512, 256, 0, stream>>>(J, hi, Jpart, h_raw, Sg, Dg,
                                   j_gamma, j_beta, h_gamma, h_beta, t, tacc);
    kd_out<<<512, 256, 0, stream>>>(tacc, t, bnH_gamma, bnH_beta, out);
}

// Round 2
// 92.675 us; speedup vs baseline: 1.0488x; 1.0488x over previous
//
#include <hip/hip_runtime.h>

// Problem: B=4, H=8, L=128, D=64. All fp32.  n = b*8+h in [0,32).
// K0: per-row softmax(K), entropy(V) — 4096 blocks x 1 wave. (Q-softmax
//     moved into KA: each KA wave owns exactly one Q row -> zero redundancy.)
// KA: Q-softmax (own 4 rows, in-register) + J via JSD identity,
//     1024 blocks x 4-row tiles, pK staged via float4 (pad 65).
// KC: per-head stats redundantly per block, gate x via S/D algebra, T=J·x,
//     He, t; ONE partial pair per block -> tblk (no atomics — R1's 16-double
//     atomic target was 2 cache lines, ~512 serialized cross-XCD RMWs/line).
// KD: reduce 64 block-partials per channel with one wave-shuffle, then
//     streaming BN write.
// MATH RULES (hard-won):
//   * __log2f/__expf/__fdividef — HIP fast intrinsics -> native v_log/v_exp/
//     v_rcp. These are the ONLY fast transcendental spellings that work here.
//   * plain log2f/exp2f -> OCML precise (~25 VALU) — R8's 51us ka_J.
//   * __exp2f -> glibc collision, compile error (R7).
//   * __builtin_amdgcn_logf / inline-asm v_log_f32 -> container death (R5/R6/R9).

#define EPS 1e-6f
#define BN_EPS 1e-5f

// ---------------- K0: 4096 blocks x 64 threads -------------------------------
// One wave per (b,h,l) row: softmax(K)->pK,Sk; entropy(V)->hi,h_raw.
__global__ void __launch_bounds__(64) k0_rows(
    const float* __restrict__ K, const float* __restrict__ V,
    float* __restrict__ pK, float* __restrict__ Sk,
    float* __restrict__ hi, float* __restrict__ h_raw)
{
    const int r = blockIdx.x;          // 0..4095
    const int lane = threadIdx.x;      // 0..63
    const int base = r * 64 + lane;

    // K softmax + Sk
    float kk = K[base];
    float m = kk;
    for (int off = 32; off; off >>= 1) m = fmaxf(m, __shfl_xor(m, off));
    float e = __expf(kk - m);
    float s = e;
    for (int off = 32; off; off >>= 1) s += __shfl_xor(s, off);
    const float pk = e * __fdividef(1.0f, s);
    pK[base] = pk;
    float pl = pk * __log2f(pk);
    for (int off = 32; off; off >>= 1) pl += __shfl_xor(pl, off);
    if (lane == 0) Sk[r] = pl;

    // V entropy
    float v = V[base];
    s = v;
    for (int off = 32; off; off >>= 1) s += __shfl_xor(s, off);
    float vn = v * __fdividef(1.0f, s + EPS);
    vn = fminf(fmaxf(vn, EPS), 1.0f);
    const float hv = -vn * __log2f(vn);
    hi[base] = hv;
    float hs = hv;
    for (int off = 32; off; off >>= 1) hs += __shfl_xor(hs, off);
    if (lane == 0) h_raw[r] = hs;
}

// ---------------- KA: 1024 blocks x 256 threads ------------------------------
// Block = (n, 4-row tile). Wave w owns row gi=i0+w: computes softmax(Q-row)
// in-register (pq -> sQ, Sq -> bq broadcast via xor-shuffles), stages pK
// head-slice into LDS (float4, pad 65), then
// J = 0.5*(Sq(i)+Sk(j) - sum_d s*log2(s/2+EPS)), s=q+k; lane -> cols
// {lane, lane+64}.
__global__ void __launch_bounds__(256) ka_J(
    const float* __restrict__ Q, const float* __restrict__ pK,
    const float* __restrict__ Sk,
    float* __restrict__ J, float* __restrict__ Sg, float* __restrict__ Dg,
    double* __restrict__ Jpart)
{
    __shared__ float sK[128 * 65];   // pad 65 -> conflict-free strided reads
    __shared__ float sQ[4 * 64];
    __shared__ float sSk[128];
    __shared__ double sred[8];
    const int bid = blockIdx.x;      // n*32 + tile
    const int n = bid >> 5;
    const int i0 = (bid & 31) * 4;
    const int tid = threadIdx.x;
    const int wave = tid >> 6, lane = tid & 63;
    const int gi = i0 + wave;        // row within head
    const int R = n * 128 + gi;      // global row

    // Q softmax for this wave's own row (replaces k0's pQ/Sq pipeline)
    float q = Q[R * 64 + lane];
    float mq = q;
    for (int off = 32; off; off >>= 1) mq = fmaxf(mq, __shfl_xor(mq, off));
    float eq = __expf(q - mq);
    float sq = eq;
    for (int off = 32; off; off >>= 1) sq += __shfl_xor(sq, off);
    const float pq = eq * __fdividef(1.0f, sq);
    sQ[wave * 64 + lane] = pq;
    float bq = pq * __log2f(pq);
    for (int off = 32; off; off >>= 1) bq += __shfl_xor(bq, off);
    // bq now holds Sq(row gi) in every lane

    // stage pK slice (128x64 = 2048 float4), pad to 65 floats/row
    const float4* pk4 = (const float4*)(pK + n * 8192);
    #pragma unroll
    for (int v = 0; v < 8; ++v) {
        const int idx = tid + 256 * v;
        const float4 f = pk4[idx];
        float* dst = sK + (idx >> 4) * 65 + (idx & 15) * 4;
        dst[0] = f.x; dst[1] = f.y; dst[2] = f.z; dst[3] = f.w;
    }
    if (tid < 128) sSk[tid] = Sk[n * 128 + tid];
    __syncthreads();

    const float* qrow = sQ + wave * 64;
    const float* kp0 = sK + lane * 65;
    const float* kp1 = sK + (lane + 64) * 65;
    float a0 = 0.f, a1 = 0.f;
    #pragma unroll 8
    for (int d = 0; d < 64; ++d) {
        const float qv = qrow[d];
        const float s0v = qv + kp0[d];
        const float s1v = qv + kp1[d];
        a0 += s0v * __log2f(fmaf(0.5f, s0v, EPS));
        a1 += s1v * __log2f(fmaf(0.5f, s1v, EPS));
    }
    const float J0 = 0.5f * (bq + sSk[lane]      - a0);
    const float J1 = 0.5f * (bq + sSk[lane + 64] - a1);
    const int rbase = R * 128;
    J[rbase + lane] = J0;
    J[rbase + lane + 64] = J1;

    // row sum + diagonal (full row lives in this wave)
    float s0 = J0 + J1;
    for (int off = 32; off; off >>= 1) s0 += __shfl_xor(s0, off);
    const float D = (gi < 64) ? __shfl(J0, gi) : __shfl(J1, gi - 64);
    if (lane == 0) { Sg[R] = s0; Dg[R] = D; }

    // off-diagonal double partials
    double ls = 0.0, ls2 = 0.0;
    if (lane != gi)      { ls += J0; ls2 += (double)J0 * (double)J0; }
    if (lane + 64 != gi) { ls += J1; ls2 += (double)J1 * (double)J1; }
    for (int off = 32; off; off >>= 1) {
        ls  += __shfl_xor(ls, off);
        ls2 += __shfl_xor(ls2, off);
    }
    if (lane == 0) { sred[wave] = ls; sred[4 + wave] = ls2; }
    __syncthreads();
    if (tid == 0) {
        Jpart[2 * bid]     = sred[0] + sred[1] + sred[2] + sred[3];
        Jpart[2 * bid + 1] = sred[4] + sred[5] + sred[6] + sred[7];
    }
}

// ---------------- KC: 512 blocks x 256 threads -------------------------------
// Redundant per-head prep (jstats from 128 partials, hstats, gate x via S/D
// algebra), then T = J·x for own 8 rows, He, t; one partial pair per block
// into tblk (no atomics, no zero-init needed — every slot fully written).
__global__ void __launch_bounds__(256) kc_he(
    const float* __restrict__ J, const float* __restrict__ hi,
    const double* __restrict__ Jpart, const float* __restrict__ h_raw,
    const float* __restrict__ Sg, const float* __restrict__ Dg,
    const float* __restrict__ j_gamma, const float* __restrict__ j_beta,
    const float* __restrict__ h_gamma, const float* __restrict__ h_beta,
    float* __restrict__ t, double* __restrict__ tblk)
{
    __shared__ float sx[128], shbn[128];
    __shared__ double sred[8];
    __shared__ double st1[4], st2[4];
    __shared__ float sprm[5];        // jm, jinv, hm, hinv, C
    const int bid = blockIdx.x;
    const int n = bid >> 4;
    const int i0 = (bid & 15) * 8;
    const int hh = n & 7;
    const int tid = threadIdx.x;
    const int wave = tid >> 6, lane = tid & 63;

    // jstats: combine the head's 128 double partials (wave 0, 2 per lane)
    if (wave == 0) {
        const int p1 = lane, p2 = lane + 64;
        const int pb1 = ((p1 >> 5) * 8 + hh) * 32 + (p1 & 31);
        const int pb2 = ((p2 >> 5) * 8 + hh) * 32 + (p2 & 31);
        double s = Jpart[2 * pb1] + Jpart[2 * pb2];
        double s2 = Jpart[2 * pb1 + 1] + Jpart[2 * pb2 + 1];
        for (int off = 32; off; off >>= 1) {
            s += __shfl_xor(s, off); s2 += __shfl_xor(s2, off);
        }
        if (lane == 0) {
            const double cnt = 65024.0;          // 4*128*127
            const double mean = s / cnt;
            const double var = s2 / cnt - mean * mean;
            sprm[0] = (float)mean;
            sprm[1] = (float)(1.0 / sqrt(var + (double)BN_EPS));
        }
    }
    // h stats over 512 values (all waves)
    {
        double s = 0.0, s2 = 0.0;
        for (int p = tid; p < 512; p += 256) {
            const int b = p >> 7, l = p & 127;
            const float v = h_raw[(b * 8 + hh) * 128 + l];
            s += v; s2 += (double)v * (double)v;
        }
        for (int off = 32; off; off >>= 1) {
            s += __shfl_xor(s, off); s2 += __shfl_xor(s2, off);
        }
        if (lane == 0) { sred[wave] = s; sred[4 + wave] = s2; }
    }
    __syncthreads();
    if (tid == 0) {
        const double hs = sred[0] + sred[1] + sred[2] + sred[3];
        const double hs2 = sred[4] + sred[5] + sred[6] + sred[7];
        const double hm = hs / 512.0;
        const double hvar = hs2 / 512.0 - hm * hm;
        sprm[2] = (float)hm;
        sprm[3] = (float)(1.0 / sqrt(hvar + (double)BN_EPS));
    }
    __syncthreads();
    const float jm = sprm[0], jinv = sprm[1];
    const float hm = sprm[2], hinv = sprm[3];
    const float jg = j_gamma[hh], jb = j_beta[hh];
    // gate x + h_bn for all 128 rows (O(1) each via S/D algebra)
    if (tid < 128) {
        const int i = tid;
        const float S = Sg[n * 128 + i], D = Dg[n * 128 + i];
        const float hb = (h_raw[n * 128 + i] - hm) * hinv * h_gamma[hh] + h_beta[hh];
        const float rs = jinv * jg * (S - D - 127.0f * jm) + 127.0f * jb + D;
        sx[i] = (rs + hb < 0.0f) ? 1.0f : 0.0f;
        shbn[i] = hb;
    }
    __syncthreads();
    if (wave == 0) {                 // C = sum of gates
        float c = sx[lane] + sx[lane + 64];
        for (int off = 32; off; off >>= 1) c += __shfl_xor(c, off);
        if (lane == 0) sprm[4] = c;
    }
    __syncthreads();
    const float C = sprm[4];
    // He, t for own 8 rows; wave rb -> local rows {rb, rb+4}
    const int rb = wave;
    double bs = 0.0, bs2 = 0.0;
    for (int rr = 0; rr < 2; ++rr) {
        const int i = i0 + rb + 4 * rr;          // row within head
        const int r = n * 128 + i;
        float tr = J[r * 128 + lane] * sx[lane] + J[r * 128 + 64 + lane] * sx[lane + 64];
        for (int off = 32; off; off >>= 1) tr += __shfl_xor(tr, off);
        const float xi = sx[i], Di = Dg[r];
        const float dot = jinv * jg * (tr - xi * Di - jm * (C - xi))
                        + jb * (C - xi) + xi * Di;
        const float He = xi * (dot + shbn[i]);
        const float tv = -(He * hi[r * 64 + lane] * __fdividef(1.0f, shbn[i]));
        t[r * 64 + lane] = tv;
        double ds = tv, ds2 = (double)tv * (double)tv;
        for (int off = 32; off; off >>= 1) {
            ds += __shfl_xor(ds, off); ds2 += __shfl_xor(ds2, off);
        }
        if (lane == 0) { bs += ds; bs2 += ds2; }
    }
    if (lane == 0) { st1[wave] = bs; st2[wave] = bs2; }
    __syncthreads();
    if (tid == 0) {
        tblk[2 * bid]     = st1[0] + st1[1] + st1[2] + st1[3];
        tblk[2 * bid + 1] = st2[0] + st2[1] + st2[2] + st2[3];
    }
}

// ---------------- KD: 512 blocks x 256 threads -------------------------------
// Wave 0 reduces the channel's 64 block-partials (b in 0..3, tile in 0..15)
// with xor-shuffles; then streaming BN write of 512 outputs.
__global__ void __launch_bounds__(256) kd_out(
    const double* __restrict__ tblk, const float* __restrict__ t,
    const float* __restrict__ gamma, const float* __restrict__ beta,
    float* __restrict__ out)
{
    __shared__ double sm[2];
    const int bid = blockIdx.x;
    const int tid = threadIdx.x;
    const int g0 = bid * 512;              // 512 outputs per block
    const int hh = (g0 >> 13) & 7;         // uniform within block
    if (tid < 64) {                        // wave 0: 64 partial pairs
        const int b = tid >> 4, tile = tid & 15;
        const int cb = ((b * 8 + hh) << 4) + tile;   // kc block id
        double s = tblk[2 * cb], s2 = tblk[2 * cb + 1];
        for (int off = 32; off; off >>= 1) {
            s += __shfl_xor(s, off); s2 += __shfl_xor(s2, off);
        }
        if (tid == 0) { sm[0] = s; sm[1] = s2; }
    }
    __syncthreads();
    const double mean = sm[0] / 32768.0;
    const double var = sm[1] / 32768.0 - mean * mean;
    const float tm = (float)mean;
    const float tinv = (float)(1.0 / sqrt(var + (double)BN_EPS));
    const float g = gamma[hh], be = beta[hh];
    out[g0 + tid]       = (t[g0 + tid]       - tm) * tinv * g + be;
    out[g0 + 256 + tid] = (t[g0 + 256 + tid] - tm) * tinv * g + be;
}

// ---------------------------------------------------------------- launch
extern "C" void kernel_launch(void* const* d_in, const int* in_sizes, int n_in,
                              void* d_out, int out_size, void* d_ws, size_t ws_size,
                              hipStream_t stream) {
    (void)in_sizes; (void)n_in; (void)out_size; (void)ws_size;
    const float* Q = (const float*)d_in[0];
    const float* K = (const float*)d_in[1];
    const float* V = (const float*)d_in[2];
    const float* j_gamma = (const float*)d_in[3];
    const float* j_beta  = (const float*)d_in[4];
    const float* h_gamma = (const float*)d_in[5];
    const float* h_beta  = (const float*)d_in[6];
    const float* bnH_gamma = (const float*)d_in[7];
    const float* bnH_beta  = (const float*)d_in[8];
    float* out = (float*)d_out;

    float* w = (float*)d_ws;
    float*  J     = w;                         // 524288
    float*  hi    = w + 524288;                // 262144
    float*  t     = w + 786432;                // 262144
    float*  pK    = w + 1310720;               // 262144 (16B-aligned for float4)
    float*  h_raw = w + 1572864;               // 4096
    float*  Sk    = w + 1581056;               // 4096
    float*  Sg    = w + 1585152;               // 4096
    float*  Dg    = w + 1589248;               // 4096
    double* Jpart = (double*)(w + 1593344);    // 2048 doubles (8B-aligned)
    double* tblk  = (double*)(w + 1597440);    // 1024 doubles (8B-aligned)

    k0_rows<<<4096, 64, 0, stream>>>(K, V, pK, Sk, hi, h_raw);
    ka_J<<<1024, 256, 0, stream>>>(Q, pK, Sk, J, Sg, Dg, Jpart);
    kc_he<<<512, 256, 0, stream>>>(J, hi, Jpart, h_raw, Sg, Dg,
                                   j_gamma, j_beta, h_gamma, h_beta, t, tblk);
    kd_out<<<512, 256, 0, stream>>>(tblk, t, bnH_gamma, bnH_beta, out);
}